// Round 17
// baseline (92.178 us; speedup 1.0000x reference)
//
#include <hip/hip_runtime.h>
#include <stdint.h>

#define BN_ 8192
#define DK_ 256
#define LOG2E 1.4426950408889634f
// int8 quantization: q = round(127*x); dot fits i32 exactly
#define INVQ (1.0f / 16129.0f)          // 1/127^2: acc -> natural-units sim
#define KQ   (LOG2E / 16129.0f)          // acc -> log2-units sim

typedef __attribute__((ext_vector_type(4))) float f32x4;
typedef __attribute__((ext_vector_type(4))) int i32x4;

// async global->LDS, 16B/lane; LDS dest wave-uniform base + lane*16, global src per-lane
#define GLD16(gp, lp)                                                   \
  __builtin_amdgcn_global_load_lds(                                     \
      (__attribute__((address_space(1))) void*)(gp),                    \
      (__attribute__((address_space(3))) void*)(lp), 16, 0, 0)

#define BAR() __builtin_amdgcn_s_barrier()
#define VM4() asm volatile("s_waitcnt vmcnt(4)" ::: "memory")
#define VM0() asm volatile("s_waitcnt vmcnt(0)" ::: "memory")

// ---------------- Kernel 1: row-normalize fp32 -> int8 (x127) ----------------
__global__ __launch_bounds__(256) void norm_kernel(
    const float* __restrict__ hf, const float* __restrict__ lf,
    const float* __restrict__ af, unsigned char* __restrict__ qbase) {
  const int tid = threadIdx.x;
  const int w = tid >> 6, lane = tid & 63;
  const int grow = blockIdx.x * 4 + w;
  const int m = grow >> 13;
  const int r = grow & (BN_ - 1);
  const float* src = (m == 0) ? hf : (m == 1) ? lf : af;
  unsigned char* dst = qbase + (size_t)m * BN_ * DK_;
  const float4 v = ((const float4*)(src + (size_t)r * DK_))[lane];
  float ss = v.x * v.x + v.y * v.y + v.z * v.z + v.w * v.w;
#pragma unroll
  for (int mk = 32; mk >= 1; mk >>= 1) ss += __shfl_xor(ss, mk, 64);
  const float inv = 127.0f / fmaxf(sqrtf(ss), 1e-8f);
  const int q0 = (int)rintf(v.x * inv), q1 = (int)rintf(v.y * inv);
  const int q2 = (int)rintf(v.z * inv), q3 = (int)rintf(v.w * inv);
  const unsigned pk = (q0 & 255) | ((q1 & 255) << 8) | ((q2 & 255) << 16) |
                      ((unsigned)(q3 & 255) << 24);
  *(unsigned*)(dst + (size_t)r * DK_ + lane * 4) = pk;
}

// ---------------- Kernel 2: fused int8-GEMM + exp2-row-sum + diag ----------------
// A = [hq;lq] stacked [16384,256] i8, B = aq [8192,256] i8, S = A·B^T (i32 exact).
// 256 blocks, 512 thr (8 waves 2Mx4N), tile 256x256, 8 col-tiles/block,
// 32 BK=64 units. LDS: 4-slot queue, 32KB/slot (A16K+B16K, XOR-swizzled).
// R17 ordering (m201-style): per unit
//   {reads bf,af0 (slot u); STAGE(u+2); vmcnt(4); BAR; MFMA; reads af1; MFMA}
// Reads are issued BEFORE the barrier -> they execute on the LDS pipe while
// straggler waves still run MFMA(u-1): cross-wave read||MFMA overlap that the
// old reads-after-barrier order serialized (R16: pipes ran in SUM).
//  RAW(reads u): slot u collectivized at unit u-1's {vmcnt(4);BAR} (my
//    STAGE(u) retired, barrier makes it collective -- R8-proven gate order).
//  WAR(STAGE u+2 overwrites slot u-2): reads(u-2) drained (lgkm before
//    MFMA(u-2)) before BAR(u-1), which all waves passed.
__global__ __launch_bounds__(512, 2) void gemm_lse_kernel(
    const unsigned char* __restrict__ hl, const unsigned char* __restrict__ an,
    float* __restrict__ sumexp /*[16384]*/, float* __restrict__ diag /*[16384]*/) {
  extern __shared__ char lds[];  // 4 * 32KB = 128KB

  const int tid = threadIdx.x;
  const int lane = tid & 63, w = tid >> 6;
  const int wr = w >> 2, wc = w & 3;
  const int lmod = lane & 15, lhalf = lane >> 4;

  const int bid = blockIdx.x;
  const int swz = (bid & 7) * 32 + (bid >> 3);  // bijective on 256, XCD-grouping
  const int mt = swz >> 2;                      // row tile 0..63
  const int cg = swz & 3;                       // col group (8 tiles each)

  // ---- stage-side constants (R16-verified int8 layout) ----
  const int rb = w * 32 + (lane >> 2);
  const int slog16 = (((lane & 3) ^ ((lane >> 3) & 3))) * 16;
  const unsigned char* aS0 = hl + ((size_t)(mt * 256 + rb)) * DK_ + slog16;
  const unsigned char* bS0 = an + (size_t)rb * DK_ + slog16;
  char* ldsS = lds + w * 2048 + lane * 16;

  // ---- read-side constants ----
  const int rdoff = lmod * 64 + 16 * (lhalf ^ ((lmod >> 1) & 3));
  const int aoffb = wr * 8192 + rdoff;
  const int boffb = 16384 + wc * 4096 + rdoff;

#define STAGE(uu)                                                        \
  do {                                                                   \
    const int u_ = (uu) & 31;                                            \
    const int kb_ = (u_ & 3) * 64;                                       \
    const size_t nto_ = (size_t)(cg * 8 + (u_ >> 2)) * 65536 + kb_;      \
    char* d_ = ldsS + (((uu) & 3) * 32768);                              \
    GLD16(aS0 + kb_, d_);                                                \
    GLD16(aS0 + 4096 + kb_, d_ + 1024);                                  \
    GLD16(bS0 + nto_, d_ + 16384);                                       \
    GLD16(bS0 + 4096 + nto_, d_ + 16384 + 1024);                         \
  } while (0)

#define LD16(dst, base, off) dst = *(const i32x4*)((base) + (off))

  float rsum[8][4];
#pragma unroll
  for (int m = 0; m < 8; ++m)
#pragma unroll
    for (int r = 0; r < 4; ++r) rsum[m][r] = 0.0f;

  // prologue: fill pipeline 2 units deep; gate unit 0; collectivize
  STAGE(0);
  STAGE(1);
  VM4();   // STAGE(0) retired (only STAGE(1)'s 4 loads may fly)
  BAR();   // slot 0 resident collectively

#pragma unroll 1
  for (int i = 0; i < 8; ++i) {   // 8 col-tiles, 4 BK=64 units each
    i32x4 acc[8][4];
#pragma unroll
    for (int m = 0; m < 8; ++m)
#pragma unroll
      for (int n = 0; n < 4; ++n) acc[m][n] = i32x4{0, 0, 0, 0};

#pragma unroll
    for (int uu = 0; uu < 4; ++uu) {
      const int u = i * 4 + uu;
      const char* L = lds + ((u & 3) * 32768);

      // ---- reads BEFORE the barrier: overlap other waves' MFMA(u-1) ----
      i32x4 bf[4], af0[4];
#pragma unroll
      for (int n = 0; n < 4; ++n) LD16(bf[n], L, boffb + n * 1024);
#pragma unroll
      for (int m = 0; m < 4; ++m) LD16(af0[m], L, aoffb + m * 1024);

      if (u + 2 < 32) {
        STAGE(u + 2);
        VM4();   // STAGE(u+1) retired -> slot u+1 resident (for next unit)
      } else if (u == 30) {
        VM0();   // drain STAGE(31)
      }
      BAR();     // collectivize slot u+1 residency; WAR fence for stages

      __builtin_amdgcn_s_setprio(1);
#pragma unroll
      for (int m = 0; m < 4; ++m)
#pragma unroll
        for (int n = 0; n < 4; ++n)
          acc[m][n] = __builtin_amdgcn_mfma_i32_16x16x64_i8(af0[m], bf[n], acc[m][n], 0, 0, 0);
      __builtin_amdgcn_s_setprio(0);

      i32x4 af1[4];
#pragma unroll
      for (int m = 0; m < 4; ++m) LD16(af1[m], L, aoffb + (m + 4) * 1024);
      __builtin_amdgcn_s_setprio(1);
#pragma unroll
      for (int m = 0; m < 4; ++m)
#pragma unroll
        for (int n = 0; n < 4; ++n)
          acc[m + 4][n] = __builtin_amdgcn_mfma_i32_16x16x64_i8(af1[m], bf[n], acc[m + 4][n], 0, 0, 0);
      __builtin_amdgcn_s_setprio(0);
    }

    // ---- tile epilogue: diag (rare) + exp2 into persistent rsum ----
    if (cg * 8 + i == (mt & 31)) {
#pragma unroll
      for (int m = 0; m < 8; ++m)
#pragma unroll
        for (int n = 0; n < 4; ++n)
#pragma unroll
          for (int r = 0; r < 4; ++r) {
            const int row_t = wr * 128 + m * 16 + lhalf * 4 + r;
            const int col_t = wc * 64 + n * 16 + lmod;
            if (row_t == col_t)
              diag[(mt >> 5) * BN_ + (mt & 31) * 256 + row_t] =
                  (float)acc[m][n][r] * INVQ;
          }
    }
#pragma unroll
    for (int m = 0; m < 8; ++m)
#pragma unroll
      for (int n = 0; n < 4; ++n)
#pragma unroll
        for (int r = 0; r < 4; ++r)
          rsum[m][r] += __builtin_amdgcn_exp2f((float)acc[m][n][r] * KQ);
  }

  // ---- final: reduce across 16 col-lanes, then atomicAdd ----
#pragma unroll
  for (int m = 0; m < 8; ++m)
#pragma unroll
    for (int r = 0; r < 4; ++r) {
      float v = rsum[m][r];
      v += __shfl_xor(v, 1, 64);
      v += __shfl_xor(v, 2, 64);
      v += __shfl_xor(v, 4, 64);
      v += __shfl_xor(v, 8, 64);
      if (lmod == 0)
        atomicAdd(&sumexp[(mt >> 5) * BN_ + (mt & 31) * 256 + wr * 128 + m * 16 + lhalf * 4 + r], v);
    }
#undef STAGE
#undef LD16
}

// ---------------- Kernel 3: CE = mean(log(sumexp) - diag) ----------------
__global__ __launch_bounds__(1024) void finalize_kernel(
    const float* __restrict__ sumexp, const float* __restrict__ diag,
    float* __restrict__ out) {
  const int tid = threadIdx.x;
  float s = 0.0f;
  for (int i = tid; i < 2 * BN_; i += 1024) s += logf(sumexp[i]) - diag[i];
#pragma unroll
  for (int mk = 32; mk >= 1; mk >>= 1) s += __shfl_xor(s, mk, 64);
  __shared__ float red[16];
  if ((tid & 63) == 0) red[tid >> 6] = s;
  __syncthreads();
  if (tid == 0) {
    float t = 0.f;
#pragma unroll
    for (int j = 0; j < 16; ++j) t += red[j];
    out[0] = t * (1.0f / (float)BN_);
  }
}

extern "C" void kernel_launch(void* const* d_in, const int* in_sizes, int n_in,
                              void* d_out, int out_size, void* d_ws, size_t ws_size,
                              hipStream_t stream) {
  const float* hf = (const float*)d_in[0];
  const float* lf = (const float*)d_in[1];
  const float* af = (const float*)d_in[2];

  char* ws = (char*)d_ws;
  const size_t nmat = (size_t)BN_ * DK_;                 // 2MB as i8
  unsigned char* qbase = (unsigned char*)ws;             // hq(2MB) lq(2MB) aq(2MB)
  unsigned char* hl = qbase;                             // stacked A [16384][256]
  unsigned char* an = qbase + 2 * nmat;
  float* sumexp = (float*)(ws + 3 * nmat);               // 64 KB [16384]
  float* diag = sumexp + 2 * BN_;                        // 64 KB [16384]

  hipFuncSetAttribute((const void*)gemm_lse_kernel,
                      hipFuncAttributeMaxDynamicSharedMemorySize, 131072);

  hipMemsetAsync(sumexp, 0, 2 * BN_ * sizeof(float), stream);
  norm_kernel<<<(3 * BN_) / 4, 256, 0, stream>>>(hf, lf, af, qbase);
  gemm_lse_kernel<<<256, 512, 131072, stream>>>(hl, an, sumexp, diag);
  finalize_kernel<<<1, 1024, 0, stream>>>(sumexp, diag, (float*)d_out);
}

// Round 18
// 76.921 us; speedup vs baseline: 1.1984x; 1.1984x over previous
//
#include <hip/hip_runtime.h>
#include <stdint.h>

#define BN_ 8192
#define DK_ 256
#define LOG2E 1.4426950408889634f
// int8 quantization: q = round(127*x); dot fits i32 exactly
#define INVQ (1.0f / 16129.0f)          // 1/127^2: acc -> natural-units sim
#define KQ   (LOG2E / 16129.0f)          // acc -> log2-units sim

typedef __attribute__((ext_vector_type(4))) float f32x4;
typedef __attribute__((ext_vector_type(4))) int i32x4;

// async global->LDS, 16B/lane; LDS dest wave-uniform base + lane*16, global src per-lane
#define GLD16(gp, lp)                                                   \
  __builtin_amdgcn_global_load_lds(                                     \
      (__attribute__((address_space(1))) void*)(gp),                    \
      (__attribute__((address_space(3))) void*)(lp), 16, 0, 0)

#define BAR() __builtin_amdgcn_s_barrier()
#define VM0() asm volatile("s_waitcnt vmcnt(0)" ::: "memory")

// ---------------- Kernel 1: row-normalize fp32 -> int8 (x127); also zeroes sumexp ----------------
__global__ __launch_bounds__(256) void norm_kernel(
    const float* __restrict__ hf, const float* __restrict__ lf,
    const float* __restrict__ af, unsigned char* __restrict__ qbase,
    float* __restrict__ sumexp) {
  const int tid = threadIdx.x;
  // fold the old hipMemsetAsync(sumexp): blocks 0..15 zero 1024 floats each
  if (blockIdx.x < 16) {
    f32x4 z = {0.f, 0.f, 0.f, 0.f};
    *(f32x4*)(sumexp + blockIdx.x * 1024 + tid * 4) = z;
  }
  const int w = tid >> 6, lane = tid & 63;
  const int grow = blockIdx.x * 4 + w;
  const int m = grow >> 13;
  const int r = grow & (BN_ - 1);
  const float* src = (m == 0) ? hf : (m == 1) ? lf : af;
  unsigned char* dst = qbase + (size_t)m * BN_ * DK_;
  const float4 v = ((const float4*)(src + (size_t)r * DK_))[lane];
  float ss = v.x * v.x + v.y * v.y + v.z * v.z + v.w * v.w;
#pragma unroll
  for (int mk = 32; mk >= 1; mk >>= 1) ss += __shfl_xor(ss, mk, 64);
  const float inv = 127.0f / fmaxf(sqrtf(ss), 1e-8f);
  const int q0 = (int)rintf(v.x * inv), q1 = (int)rintf(v.y * inv);
  const int q2 = (int)rintf(v.z * inv), q3 = (int)rintf(v.w * inv);
  const unsigned pk = (q0 & 255) | ((q1 & 255) << 8) | ((q2 & 255) << 16) |
                      ((unsigned)(q3 & 255) << 24);
  *(unsigned*)(dst + (size_t)r * DK_ + lane * 4) = pk;
}

// ---------------- Kernel 2: fused int8-GEMM + exp2-row-sum + diag (R16 exact) ----------------
// A = [hq;lq] stacked [16384,256] i8, B = aq [8192,256] i8, S = A·B^T (i32 exact).
// 256 blocks, 512 thr (8 waves 2Mx4N), tile 256x256, 8 col-tiles/block,
// 32 BK=64 units in 16 windows of 2 units. LDS: 4-slot queue, 32KB/slot
// (A16K+B16K, 16B-slot XOR swizzle by (row>>1)&3; pre-swizzled global src).
// Window: {VM0; BAR; UNIT(u)+STAGE(u+2); UNIT(u+1)+STAGE(u+3)}.
// Family note (R14/R15/R17 evidence): barrier count dominates; 2-unit windows
// with depth-2 staging are the optimum reachable with 128KB LDS.
__global__ __launch_bounds__(512, 2) void gemm_lse_kernel(
    const unsigned char* __restrict__ hl, const unsigned char* __restrict__ an,
    float* __restrict__ sumexp /*[16384]*/, float* __restrict__ diag /*[16384]*/) {
  extern __shared__ char lds[];  // 4 * 32KB = 128KB

  const int tid = threadIdx.x;
  const int lane = tid & 63, w = tid >> 6;
  const int wr = w >> 2, wc = w & 3;
  const int lmod = lane & 15, lhalf = lane >> 4;

  const int bid = blockIdx.x;
  const int swz = (bid & 7) * 32 + (bid >> 3);  // bijective on 256, XCD-grouping
  const int mt = swz >> 2;                      // row tile 0..63
  const int cg = swz & 3;                       // col group (8 tiles each)

  // ---- stage-side constants (R16-verified int8 layout) ----
  const int rb = w * 32 + (lane >> 2);
  const int slog16 = (((lane & 3) ^ ((lane >> 3) & 3))) * 16;
  const unsigned char* aS0 = hl + ((size_t)(mt * 256 + rb)) * DK_ + slog16;
  const unsigned char* bS0 = an + (size_t)rb * DK_ + slog16;
  char* ldsS = lds + w * 2048 + lane * 16;

  // ---- read-side constants ----
  const int rdoff = lmod * 64 + 16 * (lhalf ^ ((lmod >> 1) & 3));
  const int aoffb = wr * 8192 + rdoff;
  const int boffb = 16384 + wc * 4096 + rdoff;

#define STAGE(uu)                                                        \
  do {                                                                   \
    const int u_ = (uu) & 31;                                            \
    const int kb_ = (u_ & 3) * 64;                                       \
    const size_t nto_ = (size_t)(cg * 8 + (u_ >> 2)) * 65536 + kb_;      \
    char* d_ = ldsS + (((uu) & 3) * 32768);                              \
    GLD16(aS0 + kb_, d_);                                                \
    GLD16(aS0 + 4096 + kb_, d_ + 1024);                                  \
    GLD16(bS0 + nto_, d_ + 16384);                                       \
    GLD16(bS0 + 4096 + nto_, d_ + 16384 + 1024);                         \
  } while (0)

#define LD16(dst, base, off) dst = *(const i32x4*)((base) + (off))

// one BK=64 unit: 12 x b128 reads, optional stage, 32 x mfma_i32_16x16x64_i8
#define UNIT(U, DO_STAGE)                                                \
  do {                                                                   \
    const char* L = lds + (((U) & 3) * 32768);                           \
    i32x4 bf[4], af0[4], af1[4];                                         \
    _Pragma("unroll") for (int n = 0; n < 4; ++n)                        \
        LD16(bf[n], L, boffb + n * 1024);                                \
    _Pragma("unroll") for (int m = 0; m < 4; ++m)                        \
        LD16(af0[m], L, aoffb + m * 1024);                               \
    if (DO_STAGE) STAGE((U) + 2);                                        \
    __builtin_amdgcn_s_setprio(1);                                       \
    _Pragma("unroll") for (int m = 0; m < 4; ++m)                        \
    _Pragma("unroll") for (int n = 0; n < 4; ++n)                        \
        acc[m][n] = __builtin_amdgcn_mfma_i32_16x16x64_i8(               \
            af0[m], bf[n], acc[m][n], 0, 0, 0);                          \
    __builtin_amdgcn_s_setprio(0);                                       \
    _Pragma("unroll") for (int m = 0; m < 4; ++m)                        \
        LD16(af1[m], L, aoffb + (m + 4) * 1024);                         \
    __builtin_amdgcn_s_setprio(1);                                       \
    _Pragma("unroll") for (int m = 0; m < 4; ++m)                        \
    _Pragma("unroll") for (int n = 0; n < 4; ++n)                        \
        acc[m + 4][n] = __builtin_amdgcn_mfma_i32_16x16x64_i8(           \
            af1[m], bf[n], acc[m + 4][n], 0, 0, 0);                      \
    __builtin_amdgcn_s_setprio(0);                                       \
  } while (0)

  float rsum[8][4];
#pragma unroll
  for (int m = 0; m < 8; ++m)
#pragma unroll
    for (int r = 0; r < 4; ++r) rsum[m][r] = 0.0f;

  // prologue: fill pipeline 2 units deep
  STAGE(0);
  STAGE(1);

#pragma unroll 1
  for (int i = 0; i < 8; ++i) {   // 8 col-tiles; 4 BK=64 units each = 2 windows
    i32x4 acc[8][4];
#pragma unroll
    for (int m = 0; m < 8; ++m)
#pragma unroll
      for (int n = 0; n < 4; ++n) acc[m][n] = i32x4{0, 0, 0, 0};

#pragma unroll
    for (int ww = 0; ww < 2; ++ww) {
      const int u = i * 4 + ww * 2;
      VM0();   // my stages u,u+1 (issued a full window ago) retired
      BAR();   // collective: slots u,u+1 resident; window w-1 reads done
      UNIT(u, (u + 2 < 32));       // reads(u) | STAGE(u+2) | MFMA(u)
      UNIT(u + 1, (u + 3 < 32));   // reads(u+1) | STAGE(u+3) | MFMA(u+1)
    }

    // ---- tile epilogue: diag (rare) + exp2 into persistent rsum ----
    if (cg * 8 + i == (mt & 31)) {
#pragma unroll
      for (int m = 0; m < 8; ++m)
#pragma unroll
        for (int n = 0; n < 4; ++n)
#pragma unroll
          for (int r = 0; r < 4; ++r) {
            const int row_t = wr * 128 + m * 16 + lhalf * 4 + r;
            const int col_t = wc * 64 + n * 16 + lmod;
            if (row_t == col_t)
              diag[(mt >> 5) * BN_ + (mt & 31) * 256 + row_t] =
                  (float)acc[m][n][r] * INVQ;
          }
    }
#pragma unroll
    for (int m = 0; m < 8; ++m)
#pragma unroll
      for (int n = 0; n < 4; ++n)
#pragma unroll
        for (int r = 0; r < 4; ++r)
          rsum[m][r] += __builtin_amdgcn_exp2f((float)acc[m][n][r] * KQ);
  }

  // ---- final: reduce across 16 col-lanes, then atomicAdd ----
#pragma unroll
  for (int m = 0; m < 8; ++m)
#pragma unroll
    for (int r = 0; r < 4; ++r) {
      float v = rsum[m][r];
      v += __shfl_xor(v, 1, 64);
      v += __shfl_xor(v, 2, 64);
      v += __shfl_xor(v, 4, 64);
      v += __shfl_xor(v, 8, 64);
      if (lmod == 0)
        atomicAdd(&sumexp[(mt >> 5) * BN_ + (mt & 31) * 256 + wr * 128 + m * 16 + lhalf * 4 + r], v);
    }
#undef STAGE
#undef LD16
#undef UNIT
}

// ---------------- Kernel 3: CE = mean(log(sumexp) - diag) ----------------
__global__ __launch_bounds__(1024) void finalize_kernel(
    const float* __restrict__ sumexp, const float* __restrict__ diag,
    float* __restrict__ out) {
  const int tid = threadIdx.x;
  float s = 0.0f;
  for (int i = tid; i < 2 * BN_; i += 1024) s += logf(sumexp[i]) - diag[i];
#pragma unroll
  for (int mk = 32; mk >= 1; mk >>= 1) s += __shfl_xor(s, mk, 64);
  __shared__ float red[16];
  if ((tid & 63) == 0) red[tid >> 6] = s;
  __syncthreads();
  if (tid == 0) {
    float t = 0.f;
#pragma unroll
    for (int j = 0; j < 16; ++j) t += red[j];
    out[0] = t * (1.0f / (float)BN_);
  }
}

extern "C" void kernel_launch(void* const* d_in, const int* in_sizes, int n_in,
                              void* d_out, int out_size, void* d_ws, size_t ws_size,
                              hipStream_t stream) {
  const float* hf = (const float*)d_in[0];
  const float* lf = (const float*)d_in[1];
  const float* af = (const float*)d_in[2];

  char* ws = (char*)d_ws;
  const size_t nmat = (size_t)BN_ * DK_;                 // 2MB as i8
  unsigned char* qbase = (unsigned char*)ws;             // hq(2MB) lq(2MB) aq(2MB)
  unsigned char* hl = qbase;                             // stacked A [16384][256]
  unsigned char* an = qbase + 2 * nmat;
  float* sumexp = (float*)(ws + 3 * nmat);               // 64 KB [16384]
  float* diag = sumexp + 2 * BN_;                        // 64 KB [16384]

  hipFuncSetAttribute((const void*)gemm_lse_kernel,
                      hipFuncAttributeMaxDynamicSharedMemorySize, 131072);

  norm_kernel<<<(3 * BN_) / 4, 256, 0, stream>>>(hf, lf, af, qbase, sumexp);
  gemm_lse_kernel<<<256, 512, 131072, stream>>>(hl, an, sumexp, diag);
  finalize_kernel<<<1, 1024, 0, stream>>>(sumexp, diag, (float*)d_out);
}

// Round 19
// 63.953 us; speedup vs baseline: 1.4413x; 1.2028x over previous
//
#include <hip/hip_runtime.h>
#include <stdint.h>

#define BN_ 8192
#define DK_ 256
#define LOG2E 1.4426950408889634f
// int8 quantization: q = round(127*x); dot fits i32 exactly
#define INVQ (1.0f / 16129.0f)          // 1/127^2: acc -> natural-units sim
#define KQ   (LOG2E / 16129.0f)          // acc -> log2-units sim

typedef __attribute__((ext_vector_type(4))) float f32x4;
typedef __attribute__((ext_vector_type(4))) int i32x4;

// async global->LDS, 16B/lane; LDS dest wave-uniform base + lane*16, global src per-lane
#define GLD16(gp, lp)                                                   \
  __builtin_amdgcn_global_load_lds(                                     \
      (__attribute__((address_space(1))) void*)(gp),                    \
      (__attribute__((address_space(3))) void*)(lp), 16, 0, 0)

#define BAR() __builtin_amdgcn_s_barrier()
#define VM4() asm volatile("s_waitcnt vmcnt(4)" ::: "memory")
#define VM0() asm volatile("s_waitcnt vmcnt(0)" ::: "memory")

// ---------------- Kernel 1: row-normalize fp32 -> int8 (x127); also zeroes sumexp ----------------
__global__ __launch_bounds__(256) void norm_kernel(
    const float* __restrict__ hf, const float* __restrict__ lf,
    const float* __restrict__ af, unsigned char* __restrict__ qbase,
    float* __restrict__ sumexp) {
  const int tid = threadIdx.x;
  if (blockIdx.x < 16) {   // folded memset of sumexp[16384]
    f32x4 z = {0.f, 0.f, 0.f, 0.f};
    *(f32x4*)(sumexp + blockIdx.x * 1024 + tid * 4) = z;
  }
  const int w = tid >> 6, lane = tid & 63;
  const int grow = blockIdx.x * 4 + w;
  const int m = grow >> 13;
  const int r = grow & (BN_ - 1);
  const float* src = (m == 0) ? hf : (m == 1) ? lf : af;
  unsigned char* dst = qbase + (size_t)m * BN_ * DK_;
  const float4 v = ((const float4*)(src + (size_t)r * DK_))[lane];
  float ss = v.x * v.x + v.y * v.y + v.z * v.z + v.w * v.w;
#pragma unroll
  for (int mk = 32; mk >= 1; mk >>= 1) ss += __shfl_xor(ss, mk, 64);
  const float inv = 127.0f / fmaxf(sqrtf(ss), 1e-8f);
  const int q0 = (int)rintf(v.x * inv), q1 = (int)rintf(v.y * inv);
  const int q2 = (int)rintf(v.z * inv), q3 = (int)rintf(v.w * inv);
  const unsigned pk = (q0 & 255) | ((q1 & 255) << 8) | ((q2 & 255) << 16) |
                      ((unsigned)(q3 & 255) << 24);
  *(unsigned*)(dst + (size_t)r * DK_ + lane * 4) = pk;
}

// ---------------- Kernel 2: BARRIER-FREE fused int8-GEMM + exp2-row-sum + diag ----------------
// A = [hq;lq] stacked [16384,256] i8, B = aq [8192,256] i8, S = A·B^T.
// 256 blocks = 128 mt x 2 cg; 512 thr = 8 waves (2wr x 4wc), wave tile 64x64.
// A panel (128x256B = 32KB) staged ONCE cooperatively (the kernel's only
// barrier), then all A fragments hoisted to registers (afr[4][4], 64 VGPR).
// Each wave double-buffers a PRIVATE 4KB B slice (64 cols x BK=64) in its own
// LDS region: RAW gated by the wave's own vmcnt(4), WAR by program order
// (ds_reads lgkm-drained before MFMA, which precedes next STAGEB; gld_lds
// write lands >=200cy after issue). ZERO barriers in the main loop -> the 8
// waves de-phase and MFMA/LDS/VALU overlap statistically (m114 mechanism)
// instead of running in SUM under lockstep (R14-R18: ~130k cyc invariant
// overhead regardless of work size).
// LDS: A 32KB + 8 waves x 8KB B = 96KB.
__global__ __launch_bounds__(512, 2) void gemm_lse_kernel(
    const unsigned char* __restrict__ hl, const unsigned char* __restrict__ an,
    float* __restrict__ sumexp /*[16384]*/, float* __restrict__ diag /*[16384]*/) {
  extern __shared__ char lds[];  // 96KB

  const int tid = threadIdx.x;
  const int lane = tid & 63, w = tid >> 6;
  const int wr = w >> 2, wc = w & 3;
  const int lmod = lane & 15, lhalf = lane >> 4;

  const int bid = blockIdx.x;
  const int swz = (bid & 7) * 32 + (bid >> 3);  // bijective on 256, XCD-grouping
  const int mt = swz >> 1;                      // row panel 0..127 (128 rows each)
  const int cg = swz & 1;                       // col half (16 ct of 256 cols)

  // ---- A cooperative stage: [128 rows][16 phys 16B-slots], phys = s ^ (row&15)
  const int aswz = 16 * ((tid & 15) ^ ((tid >> 4) & 15));
  const unsigned char* aG = hl + (size_t)(mt * 128 + (tid >> 4)) * DK_ + aswz;
  char* aD = lds + tid * 16;
  GLD16(aG, aD);
  GLD16(aG + 8192, aD + 8192);
  GLD16(aG + 16384, aD + 16384);
  GLD16(aG + 24576, aD + 24576);

  // ---- B private staging constants (R16-verified 64-row slice layout) ----
  const int slog16 = 16 * ((lane & 3) ^ ((lane >> 3) & 3));
  const unsigned char* bB =
      an + (size_t)(cg * 4096 + wc * 64 + (lane >> 2)) * DK_ + slog16;
  char* ldsB = lds + 32768 + w * 8192 + lane * 16;

#define STAGEB(uu)                                                       \
  do {                                                                   \
    const int ct_ = (uu) >> 2, ku_ = (uu) & 3;                           \
    const unsigned char* g_ = bB + ct_ * 65536 + ku_ * 64;               \
    char* d_ = ldsB + ((uu) & 1) * 4096;                                 \
    GLD16(g_, d_);                                                       \
    GLD16(g_ + 4096, d_ + 1024);                                         \
    GLD16(g_ + 8192, d_ + 2048);                                         \
    GLD16(g_ + 12288, d_ + 3072);                                        \
  } while (0)

  STAGEB(0);
  VM4();   // 8 outstanding (4 A + 4 B0); waits to <=4 -> A drained (B0 flies)
  BAR();   // the kernel's ONLY barrier: A collectively resident

  // ---- hoist all A fragments: afr[ku][m], row = wr*64+m*16+lmod,
  //      byte = row*256 + 16*((ku*4+lhalf) ^ (row&15)),  row&15 == lmod
  i32x4 afr[4][4];
  {
    const char* aR = lds + (wr * 64 + lmod) * 256;
#pragma unroll
    for (int ku = 0; ku < 4; ++ku)
#pragma unroll
      for (int m = 0; m < 4; ++m)
        afr[ku][m] = *(const i32x4*)(aR + m * 4096 + 16 * ((ku * 4 + lhalf) ^ lmod));
  }

  const int rdoffB = lmod * 64 + 16 * (lhalf ^ ((lmod >> 1) & 3));
  const char* ldsBr = lds + 32768 + w * 8192;

  // diag geometry: D = 64-aligned col block equal to this wave's row block
  const int p = mt >> 6;
  const int D = (mt & 63) * 128 + wr * 64;
  const bool dWave = (wc == ((D >> 6) & 3)) && ((D >> 12) == cg);
  const int ctD = (D >> 8) & 15;

  float rsum[4][4];
#pragma unroll
  for (int m = 0; m < 4; ++m)
#pragma unroll
    for (int r = 0; r < 4; ++r) rsum[m][r] = 0.0f;

#pragma unroll 1
  for (int ct = 0; ct < 16; ++ct) {
    i32x4 acc[4][4];
#pragma unroll
    for (int m = 0; m < 4; ++m)
#pragma unroll
      for (int n = 0; n < 4; ++n) acc[m][n] = i32x4{0, 0, 0, 0};

#pragma unroll
    for (int ku = 0; ku < 4; ++ku) {
      const int u = ct * 4 + ku;
      if (u < 63) {
        STAGEB(u + 1);
        VM4();   // my B(u) landed (only B(u+1)'s 4 loads may remain)
      } else {
        VM0();   // last unit: drain B(63)
      }
      const char* Lb = ldsBr + (ku & 1) * 4096;
      i32x4 bf[4];
#pragma unroll
      for (int n = 0; n < 4; ++n) bf[n] = *(const i32x4*)(Lb + n * 1024 + rdoffB);
      __builtin_amdgcn_s_setprio(1);
#pragma unroll
      for (int m = 0; m < 4; ++m)
#pragma unroll
        for (int n = 0; n < 4; ++n)
          acc[m][n] = __builtin_amdgcn_mfma_i32_16x16x64_i8(afr[ku][m], bf[n], acc[m][n], 0, 0, 0);
      __builtin_amdgcn_s_setprio(0);
    }

    // ---- tile epilogue: diag (rare) + exp2 into persistent rsum ----
    if (dWave && ct == ctD) {
#pragma unroll
      for (int m = 0; m < 4; ++m)
#pragma unroll
        for (int r = 0; r < 4; ++r)
          if (lmod == lhalf * 4 + r)
            diag[p * BN_ + D + m * 16 + lmod] = (float)acc[m][m][r] * INVQ;
    }
#pragma unroll
    for (int m = 0; m < 4; ++m)
#pragma unroll
      for (int n = 0; n < 4; ++n)
#pragma unroll
        for (int r = 0; r < 4; ++r)
          rsum[m][r] += __builtin_amdgcn_exp2f((float)acc[m][n][r] * KQ);
  }

  // ---- final: reduce across 16 col-lanes, then atomicAdd ----
#pragma unroll
  for (int m = 0; m < 4; ++m)
#pragma unroll
    for (int r = 0; r < 4; ++r) {
      float v = rsum[m][r];
      v += __shfl_xor(v, 1, 64);
      v += __shfl_xor(v, 2, 64);
      v += __shfl_xor(v, 4, 64);
      v += __shfl_xor(v, 8, 64);
      if (lmod == 0)
        atomicAdd(&sumexp[p * BN_ + D + m * 16 + lhalf * 4 + r], v);
    }
#undef STAGEB
}

// ---------------- Kernel 3: CE = mean(log(sumexp) - diag) ----------------
__global__ __launch_bounds__(1024) void finalize_kernel(
    const float* __restrict__ sumexp, const float* __restrict__ diag,
    float* __restrict__ out) {
  const int tid = threadIdx.x;
  float s = 0.0f;
  for (int i = tid; i < 2 * BN_; i += 1024) s += logf(sumexp[i]) - diag[i];
#pragma unroll
  for (int mk = 32; mk >= 1; mk >>= 1) s += __shfl_xor(s, mk, 64);
  __shared__ float red[16];
  if ((tid & 63) == 0) red[tid >> 6] = s;
  __syncthreads();
  if (tid == 0) {
    float t = 0.f;
#pragma unroll
    for (int j = 0; j < 16; ++j) t += red[j];
    out[0] = t * (1.0f / (float)BN_);
  }
}

extern "C" void kernel_launch(void* const* d_in, const int* in_sizes, int n_in,
                              void* d_out, int out_size, void* d_ws, size_t ws_size,
                              hipStream_t stream) {
  const float* hf = (const float*)d_in[0];
  const float* lf = (const float*)d_in[1];
  const float* af = (const float*)d_in[2];

  char* ws = (char*)d_ws;
  const size_t nmat = (size_t)BN_ * DK_;                 // 2MB as i8
  unsigned char* qbase = (unsigned char*)ws;             // hq(2MB) lq(2MB) aq(2MB)
  unsigned char* hl = qbase;                             // stacked A [16384][256]
  unsigned char* an = qbase + 2 * nmat;
  float* sumexp = (float*)(ws + 3 * nmat);               // 64 KB [16384]
  float* diag = sumexp + 2 * BN_;                        // 64 KB [16384]

  hipFuncSetAttribute((const void*)gemm_lse_kernel,
                      hipFuncAttributeMaxDynamicSharedMemorySize, 98304);

  norm_kernel<<<(3 * BN_) / 4, 256, 0, stream>>>(hf, lf, af, qbase, sumexp);
  gemm_lse_kernel<<<256, 512, 98304, stream>>>(hl, an, sumexp, diag);
  finalize_kernel<<<1, 1024, 0, stream>>>(sumexp, diag, (float*)d_out);
}